// Round 7
// baseline (286.919 us; speedup 1.0000x reference)
//
#include <hip/hip_runtime.h>
#include <hip/hip_bf16.h>
#include <cstdint>

#define B_  4
#define S_  2048
#define H_  1024
#define NH_ 16
#define HD_ 64

using short8  = __attribute__((ext_vector_type(8))) short;
using floatx4 = __attribute__((ext_vector_type(4))) float;

__device__ __forceinline__ unsigned short f2b(float f) {
  union { float f; unsigned int u; } x; x.f = f;
  unsigned int r = x.u + 0x7fffu + ((x.u >> 16) & 1u);
  return (unsigned short)(r >> 16);
}
__device__ __forceinline__ unsigned short f2b_fast(float f) {
  union { float f; unsigned int u; } x; x.f = f;
  return (unsigned short)((x.u + 0x8000u) >> 16);
}
__device__ __forceinline__ unsigned int pack2(float a, float b) {
  return (unsigned int)f2b(a) | ((unsigned int)f2b(b) << 16);
}

// async global->LDS, 16B per lane. lds dest = wave-uniform base + lane*16.
__device__ __forceinline__ void async16(void* lds, const void* g) {
  __builtin_amdgcn_global_load_lds(
      (const __attribute__((address_space(1))) unsigned int*)g,
      (__attribute__((address_space(3))) unsigned int*)lds, 16, 0, 0);
}

// ---------- merged prologue: cast x + transpose both weights ----------
__device__ __forceinline__ void transpose_tile(const float* __restrict__ in,
                                               unsigned short* __restrict__ out,
                                               int R, int C, int c0, int r0) {
  __shared__ float tile[32][33];
  int tx = threadIdx.x & 31, ty = threadIdx.x >> 5;  // 32 x 8
  for (int i = 0; i < 4; i++) {
    int r = r0 + ty + i * 8;
    tile[ty + i * 8][tx] = in[(size_t)r * C + c0 + tx];
  }
  __syncthreads();
  for (int i = 0; i < 4; i++) {
    int c = c0 + ty + i * 8;
    out[(size_t)c * R + r0 + tx] = f2b(tile[tx][ty + i * 8]);
  }
}

__global__ void k_prep(const float* __restrict__ x, const float* __restrict__ w_qkv,
                       const float* __restrict__ w_out,
                       unsigned short* __restrict__ xb, unsigned short* __restrict__ wqkvT,
                       unsigned short* __restrict__ woutT) {
  int bx = blockIdx.x;
  if (bx < 8192) {                       // cast x: 8192 blocks * 256 thr * 4 elems
    int i = (bx * 256 + threadIdx.x) * 4;
    float4 v = *(const float4*)(x + i);
    ushort4 o;
    o.x = f2b(v.x); o.y = f2b(v.y); o.z = f2b(v.z); o.w = f2b(v.w);
    *(ushort4*)(xb + i) = o;
  } else if (bx < 8192 + 3072) {         // w_qkv [1024][3072] -> [3072][1024]
    int t = bx - 8192;
    transpose_tile(w_qkv, wqkvT, H_, 3 * H_, (t % 96) * 32, (t / 96) * 32);
  } else {                               // w_out [1024][1024] -> [1024][1024]^T
    int t = bx - 8192 - 3072;
    transpose_tile(w_out, woutT, H_, H_, (t & 31) * 32, (t >> 5) * 32);
  }
}

// ---------- bf16 MFMA GEMM, BK=32, double-buffered (32 KB LDS) ----------
template <bool OUT_BF16>
__global__ __launch_bounds__(256, 3) void k_gemm_bt(
    const unsigned short* __restrict__ A,   // [M][K] bf16
    const unsigned short* __restrict__ BT,  // [N][K] bf16
    const float* __restrict__ bias,         // [N]
    void* __restrict__ Cout,
    unsigned short* __restrict__ vt,        // V-transposed out (OUT_BF16 only)
    int M, int N, int K) {
  __shared__ __align__(16) unsigned short As[2][128 * 32];
  __shared__ __align__(16) unsigned short Bs[2][128 * 32];
  const int tid  = threadIdx.x;
  const int lane = tid & 63, wave = tid >> 6;
  const int quad = lane >> 4, l16 = lane & 15;
  const int wm = wave >> 1, wn = wave & 1;
  const int m0 = blockIdx.y * 128, n0 = blockIdx.x * 128;
  const int wv2 = wave & 1;

  const unsigned short* srcbase = (wave < 2) ? A : BT;
  const int base0 = (wave < 2) ? m0 : n0;

  floatx4 acc[4][4];
  for (int mt = 0; mt < 4; mt++)
    for (int nt = 0; nt < 4; nt++)
      acc[mt][nt] = (floatx4){0.f, 0.f, 0.f, 0.f};

  auto stage = [&](int k0, int bufi) {
    unsigned short* dst = (wave < 2) ? &As[bufi][0] : &Bs[bufi][0];
    for (int j = 0; j < 4; j++) {
      int c = wv2 * 256 + j * 64 + lane;      // stored chunk 0..511
      int row = c >> 2, slot = c & 3;
      int c8 = slot ^ ((row >> 1) & 3);       // logical 16B chunk in row
      async16(&dst[c * 8], &srcbase[(size_t)(base0 + row) * K + k0 + c8 * 8]);
    }
  };

  stage(0, 0);
  int it = 0;
  for (int k0 = 0; k0 < K; k0 += 32, it++) {
    const int cur = it & 1;
    __syncthreads();                          // buf[cur] ready (barrier drains vmcnt)
    if (k0 + 32 < K) stage(k0 + 32, cur ^ 1); // prefetch, drained at NEXT barrier
    short8 af[4], bq[4];
    for (int t = 0; t < 4; t++) {
      int ra = wm * 64 + t * 16 + l16;
      int rb = wn * 64 + t * 16 + l16;
      af[t] = *(const short8*)&As[cur][(ra * 4 + (quad ^ ((ra >> 1) & 3))) * 8];
      bq[t] = *(const short8*)&Bs[cur][(rb * 4 + (quad ^ ((rb >> 1) & 3))) * 8];
    }
    for (int mt = 0; mt < 4; mt++)
      for (int nt = 0; nt < 4; nt++)
        acc[mt][nt] = __builtin_amdgcn_mfma_f32_16x16x32_bf16(af[mt], bq[nt], acc[mt][nt], 0, 0, 0);
  }

  if (OUT_BF16 && n0 >= 2048) {
    for (int mt = 0; mt < 4; mt++) {
      int row0 = m0 + wm * 64 + mt * 16 + quad * 4;
      int b = row0 >> 11, s = row0 & 2047;
      for (int nt = 0; nt < 4; nt++) {
        int col = n0 + wn * 64 + nt * 16 + l16;
        float bv = bias[col];
        uint2 u;
        u.x = pack2(acc[mt][nt][0] + bv, acc[mt][nt][1] + bv);
        u.y = pack2(acc[mt][nt][2] + bv, acc[mt][nt][3] + bv);
        *(uint2*)&vt[(size_t)(b * 1024 + (col - 2048)) * S_ + s] = u;
      }
    }
  } else {
    for (int mt = 0; mt < 4; mt++) {
      int row = m0 + wm * 64 + mt * 16 + quad * 4;
      for (int nt = 0; nt < 4; nt++) {
        int col = n0 + wn * 64 + nt * 16 + l16;
        float bv = bias[col];
        for (int r = 0; r < 4; r++) {
          float v = acc[mt][nt][r] + bv;
          if (OUT_BF16) ((unsigned short*)Cout)[(size_t)(row + r) * N + col] = f2b(v);
          else          ((float*)Cout)[(size_t)(row + r) * N + col] = v;
        }
      }
    }
  }
}

// ---------- flash attention (causal), wave-tile 64 q-rows, 48 KB LDS ----------
// Block = 256 q rows (4 waves x 64). Grid 512: qt = bx<256 ? 7-(bx>>6) : (bx>>6)-4
// -> each CU's two resident blocks have qt summing to 7 (constant 36 kv-iters).
// LDS-pipe amortization: K/VT fragments reused across 4 g-groups per wave.
// Ps: 2 per-wave g-buffers (2 KB each); g processed in two pairs.
// launch_bounds (256,2): ~170 regs, no spill (round-5 tripwire: WRITE_SIZE).
__global__ __launch_bounds__(256, 2) void k_attn(
    const unsigned short* __restrict__ qkv,  // [B*S][3H] bf16 (Q,K valid)
    const unsigned short* __restrict__ vt,   // [B*NH*HD][S] bf16
    unsigned short* __restrict__ outb) {     // [B*S][H] bf16
  __shared__ __align__(16) unsigned short Ks [2][64 * 64];   // [kv][hd] swizzled
  __shared__ __align__(16) unsigned short VTs[2][64 * 64];   // [hd][kv] swizzled
  __shared__ __align__(16) unsigned short Ps[4][2][16 * 64]; // per-wave, 2 g-buffers

  const int tid  = threadIdx.x;
  const int lane = tid & 63, w = tid >> 6;
  const int quad = lane >> 4, l16 = lane & 15;
  const int bx = blockIdx.x;
  const int qt = (bx < 256) ? 7 - (bx >> 6) : (bx >> 6) - 4;
  const int bh = bx & 63;
  const int b = bh >> 4, h = bh & 15;
  const int qwv = qt * 256 + w * 64;          // this wave's first q row
  const int wv2 = w & 1;

  // Q B-fragments (S^T = K * Q^T): B[k=d][n=q], lane n=l16, k=kh*32+quad*8+j
  short8 qf[4][2];
  for (int g = 0; g < 4; g++)
    for (int kh = 0; kh < 2; kh++)
      qf[g][kh] = *(const short8*)&qkv[(size_t)(b * S_ + qwv + g * 16 + l16) * (3 * H_)
                                       + h * HD_ + kh * 32 + quad * 8];

  floatx4 oacc[4][4];
  float lsum[4] = {0.f, 0.f, 0.f, 0.f};
  for (int g = 0; g < 4; g++)
    for (int ct = 0; ct < 4; ct++) oacc[g][ct] = (floatx4){0.f, 0.f, 0.f, 0.f};

  auto stage = [&](int kt, int bufi) {
    if (w < 2) {
      for (int j = 0; j < 4; j++) {
        int c = wv2 * 256 + j * 64 + lane;  // 0..511
        int row = c >> 3, c8 = (c & 7) ^ (row & 7);
        async16(&Ks[bufi][c * 8],
                &qkv[(size_t)(b * S_ + kt * 64 + row) * (3 * H_) + H_ + h * HD_ + c8 * 8]);
      }
    } else {
      for (int j = 0; j < 4; j++) {
        int c = wv2 * 256 + j * 64 + lane;
        int row = c >> 3, c8 = (c & 7) ^ (row & 7);
        async16(&VTs[bufi][c * 8],
                &vt[(size_t)(bh * HD_ + row) * S_ + kt * 64 + c8 * 8]);
      }
    }
  };

  const int ktmax = 4 * qt + 3;
  stage(0, 0);
  for (int kt = 0; kt <= ktmax; kt++) {
    const int cur = kt & 1;
    __syncthreads();                          // buf[cur] visible; prev reads done
    if (kt < ktmax) stage(kt + 1, cur ^ 1);   // prefetch, hidden behind compute

    if (kt * 64 <= qwv + 63) {                // wave not fully masked
      const bool need_mask = (kt * 64 + 63 > qwv);

      // V A-fragments: A[m=d][k=kv] (reused by all 4 g)
      short8 vf[4][2];
      for (int ct = 0; ct < 4; ct++)
        for (int kh = 0; kh < 2; kh++) {
          int vrow = ct * 16 + l16;
          vf[ct][kh] = *(const short8*)&VTs[cur][(vrow * 8 + ((kh * 4 + quad) ^ (vrow & 7))) * 8];
        }

      for (int gp = 0; gp < 2; gp++) {
        const int g0 = gp * 2;
        if (kt * 64 > qwv + (g0 + 1) * 16 + 15) continue;  // both g fully masked

        // S^T = K Q^T -> p -> Ps[w][gi]
        for (int ct = 0; ct < 4; ct++) {
          int krow = ct * 16 + l16;
          short8 kf0 = *(const short8*)&Ks[cur][(krow * 8 + ((0 + quad) ^ (krow & 7))) * 8];
          short8 kf1 = *(const short8*)&Ks[cur][(krow * 8 + ((4 + quad) ^ (krow & 7))) * 8];
          int slot = (ct * 2 + (quad >> 1)) ^ (l16 & 7);
          for (int gi = 0; gi < 2; gi++) {
            int g = g0 + gi;
            if (kt * 64 > qwv + g * 16 + 15) continue;     // g fully masked
            floatx4 z = (floatx4){0.f, 0.f, 0.f, 0.f};
            z = __builtin_amdgcn_mfma_f32_16x16x32_bf16(kf0, qf[g][0], z, 0, 0, 0);
            z = __builtin_amdgcn_mfma_f32_16x16x32_bf16(kf1, qf[g][1], z, 0, 0, 0);
            // lane: q = qwv+g*16+l16 fixed; kv = kt*64+ct*16+quad*4+r
            float p[4];
            if (need_mask) {
              int kvb = kt * 64 + ct * 16 + quad * 4;
              int q = qwv + g * 16 + l16;
              for (int r = 0; r < 4; r++)
                p[r] = (kvb + r <= q) ? __expf(z[r] * 0.125f) : 0.f;
            } else {
              for (int r = 0; r < 4; r++) p[r] = __expf(z[r] * 0.125f);
            }
            lsum[g] += (p[0] + p[1]) + (p[2] + p[3]);
            uint2 u;
            u.x = (unsigned int)f2b_fast(p[0]) | ((unsigned int)f2b_fast(p[1]) << 16);
            u.y = (unsigned int)f2b_fast(p[2]) | ((unsigned int)f2b_fast(p[3]) << 16);
            *(uint2*)&Ps[w][gi][l16 * 64 + slot * 8 + (quad & 1) * 4] = u;
          }
        }

        // O^T += V^T P^T (wave-private round trip; lgkmcnt by compiler)
        for (int gi = 0; gi < 2; gi++) {
          int g = g0 + gi;
          if (kt * 64 > qwv + g * 16 + 15) continue;
          for (int kh = 0; kh < 2; kh++) {
            short8 pf = *(const short8*)&Ps[w][gi][l16 * 64 + ((kh * 4 + quad) ^ (l16 & 7)) * 8];
            for (int ct = 0; ct < 4; ct++)
              oacc[g][ct] = __builtin_amdgcn_mfma_f32_16x16x32_bf16(vf[ct][kh], pf, oacc[g][ct], 0, 0, 0);
          }
        }
      }
    }
  }

  // finish row sums: reduce across quads (lanes sharing l16 share q)
  for (int g = 0; g < 4; g++) {
    lsum[g] += __shfl_xor(lsum[g], 16);
    lsum[g] += __shfl_xor(lsum[g], 32);
  }

  // epilogue: lane holds q=l16 fixed, d=ct*16+quad*4+r -> packed 8B stores
  for (int g = 0; g < 4; g++) {
    float inv = 1.0f / lsum[g];
    int q = qwv + g * 16 + l16;
    for (int ct = 0; ct < 4; ct++) {
      uint2 u;
      u.x = pack2(oacc[g][ct][0] * inv, oacc[g][ct][1] * inv);
      u.y = pack2(oacc[g][ct][2] * inv, oacc[g][ct][3] * inv);
      *(uint2*)&outb[(size_t)(b * S_ + q) * H_ + h * HD_ + ct * 16 + quad * 4] = u;
    }
  }
}

extern "C" void kernel_launch(void* const* d_in, const int* in_sizes, int n_in,
                              void* d_out, int out_size, void* d_ws, size_t ws_size,
                              hipStream_t stream) {
  const float* x     = (const float*)d_in[0];
  const float* w_qkv = (const float*)d_in[1];
  const float* b_qkv = (const float*)d_in[2];
  const float* w_out = (const float*)d_in[3];
  const float* b_out = (const float*)d_in[4];

  char* ws = (char*)d_ws;
  size_t off = 0;
  auto alloc = [&](size_t bytes) -> void* {
    void* p = ws + off;
    off = (off + bytes + 255) & ~(size_t)255;
    return p;
  };
  unsigned short* xb    = (unsigned short*)alloc((size_t)B_ * S_ * H_ * 2);
  unsigned short* wqkvT = (unsigned short*)alloc((size_t)3 * H_ * H_ * 2);
  unsigned short* woutT = (unsigned short*)alloc((size_t)H_ * H_ * 2);
  unsigned short* qkv   = (unsigned short*)alloc((size_t)B_ * S_ * 3 * H_ * 2);
  unsigned short* ao    = (unsigned short*)alloc((size_t)B_ * S_ * H_ * 2);
  unsigned short* vtb   = (unsigned short*)alloc((size_t)B_ * NH_ * HD_ * S_ * 2);

  // merged prologue: cast x (8192 blocks) + transpose w_qkv (3072) + w_out (1024)
  k_prep<<<8192 + 3072 + 1024, 256, 0, stream>>>(x, w_qkv, w_out, xb, wqkvT, woutT);

  // QKV projection; V columns go transposed straight into vtb
  k_gemm_bt<true ><<<dim3(3 * H_ / 128, B_ * S_ / 128), 256, 0, stream>>>(
      xb, wqkvT, b_qkv, qkv, vtb, B_ * S_, 3 * H_, H_);

  k_attn<<<512, 256, 0, stream>>>(qkv, vtb, ao);

  k_gemm_bt<false><<<dim3(H_ / 128, B_ * S_ / 128), 256, 0, stream>>>(
      ao, woutT, b_out, (float*)d_out, nullptr, B_ * S_, H_, H_);
}

// Round 8
// 249.689 us; speedup vs baseline: 1.1491x; 1.1491x over previous
//
#include <hip/hip_runtime.h>
#include <hip/hip_bf16.h>
#include <cstdint>

#define B_  4
#define S_  2048
#define H_  1024
#define NH_ 16
#define HD_ 64

using short8  = __attribute__((ext_vector_type(8))) short;
using floatx4 = __attribute__((ext_vector_type(4))) float;

__device__ __forceinline__ unsigned short f2b(float f) {
  union { float f; unsigned int u; } x; x.f = f;
  unsigned int r = x.u + 0x7fffu + ((x.u >> 16) & 1u);
  return (unsigned short)(r >> 16);
}
__device__ __forceinline__ unsigned short f2b_fast(float f) {
  union { float f; unsigned int u; } x; x.f = f;
  return (unsigned short)((x.u + 0x8000u) >> 16);
}
__device__ __forceinline__ unsigned int pack2(float a, float b) {
  return (unsigned int)f2b(a) | ((unsigned int)f2b(b) << 16);
}

// async global->LDS, 16B per lane. lds dest = wave-uniform base + lane*16.
__device__ __forceinline__ void async16(void* lds, const void* g) {
  __builtin_amdgcn_global_load_lds(
      (const __attribute__((address_space(1))) unsigned int*)g,
      (__attribute__((address_space(3))) unsigned int*)lds, 16, 0, 0);
}

// ---------- merged prologue: cast x + transpose both weights ----------
__device__ __forceinline__ void transpose_tile(const float* __restrict__ in,
                                               unsigned short* __restrict__ out,
                                               int R, int C, int c0, int r0) {
  __shared__ float tile[32][33];
  int tx = threadIdx.x & 31, ty = threadIdx.x >> 5;  // 32 x 8
  for (int i = 0; i < 4; i++) {
    int r = r0 + ty + i * 8;
    tile[ty + i * 8][tx] = in[(size_t)r * C + c0 + tx];
  }
  __syncthreads();
  for (int i = 0; i < 4; i++) {
    int c = c0 + ty + i * 8;
    out[(size_t)c * R + r0 + tx] = f2b(tile[tx][ty + i * 8]);
  }
}

__global__ void k_prep(const float* __restrict__ x, const float* __restrict__ w_qkv,
                       const float* __restrict__ w_out,
                       unsigned short* __restrict__ xb, unsigned short* __restrict__ wqkvT,
                       unsigned short* __restrict__ woutT) {
  int bx = blockIdx.x;
  if (bx < 8192) {                       // cast x: 8192 blocks * 256 thr * 4 elems
    int i = (bx * 256 + threadIdx.x) * 4;
    float4 v = *(const float4*)(x + i);
    ushort4 o;
    o.x = f2b(v.x); o.y = f2b(v.y); o.z = f2b(v.z); o.w = f2b(v.w);
    *(ushort4*)(xb + i) = o;
  } else if (bx < 8192 + 3072) {         // w_qkv [1024][3072] -> [3072][1024]
    int t = bx - 8192;
    transpose_tile(w_qkv, wqkvT, H_, 3 * H_, (t % 96) * 32, (t / 96) * 32);
  } else {                               // w_out [1024][1024] -> [1024][1024]^T
    int t = bx - 8192 - 3072;
    transpose_tile(w_out, woutT, H_, H_, (t & 31) * 32, (t >> 5) * 32);
  }
}

// ---------- bf16 MFMA GEMM, BK=32, double-buffered (32 KB LDS) ----------
// launch_bounds (256,4): VGPR 60 + 64 AGPR = 124 <= 128 -> 4 waves/SIMD,
// spill-free (verified round 5: WRITE_SIZE = outputs only).
template <bool OUT_BF16>
__global__ __launch_bounds__(256, 4) void k_gemm_bt(
    const unsigned short* __restrict__ A,   // [M][K] bf16
    const unsigned short* __restrict__ BT,  // [N][K] bf16
    const float* __restrict__ bias,         // [N]
    void* __restrict__ Cout,
    unsigned short* __restrict__ vt,        // V-transposed out (OUT_BF16 only)
    int M, int N, int K) {
  __shared__ __align__(16) unsigned short As[2][128 * 32];
  __shared__ __align__(16) unsigned short Bs[2][128 * 32];
  const int tid  = threadIdx.x;
  const int lane = tid & 63, wave = tid >> 6;
  const int quad = lane >> 4, l16 = lane & 15;
  const int wm = wave >> 1, wn = wave & 1;
  const int m0 = blockIdx.y * 128, n0 = blockIdx.x * 128;
  const int wv2 = wave & 1;

  const unsigned short* srcbase = (wave < 2) ? A : BT;
  const int base0 = (wave < 2) ? m0 : n0;

  floatx4 acc[4][4];
  for (int mt = 0; mt < 4; mt++)
    for (int nt = 0; nt < 4; nt++)
      acc[mt][nt] = (floatx4){0.f, 0.f, 0.f, 0.f};

  auto stage = [&](int k0, int bufi) {
    unsigned short* dst = (wave < 2) ? &As[bufi][0] : &Bs[bufi][0];
    for (int j = 0; j < 4; j++) {
      int c = wv2 * 256 + j * 64 + lane;      // stored chunk 0..511
      int row = c >> 2, slot = c & 3;
      int c8 = slot ^ ((row >> 1) & 3);       // logical 16B chunk in row
      async16(&dst[c * 8], &srcbase[(size_t)(base0 + row) * K + k0 + c8 * 8]);
    }
  };

  stage(0, 0);
  int it = 0;
  for (int k0 = 0; k0 < K; k0 += 32, it++) {
    const int cur = it & 1;
    __syncthreads();                          // buf[cur] ready (barrier drains vmcnt)
    if (k0 + 32 < K) stage(k0 + 32, cur ^ 1); // prefetch, drained at NEXT barrier
    short8 af[4], bq[4];
    for (int t = 0; t < 4; t++) {
      int ra = wm * 64 + t * 16 + l16;
      int rb = wn * 64 + t * 16 + l16;
      af[t] = *(const short8*)&As[cur][(ra * 4 + (quad ^ ((ra >> 1) & 3))) * 8];
      bq[t] = *(const short8*)&Bs[cur][(rb * 4 + (quad ^ ((rb >> 1) & 3))) * 8];
    }
    for (int mt = 0; mt < 4; mt++)
      for (int nt = 0; nt < 4; nt++)
        acc[mt][nt] = __builtin_amdgcn_mfma_f32_16x16x32_bf16(af[mt], bq[nt], acc[mt][nt], 0, 0, 0);
  }

  if (OUT_BF16 && n0 >= 2048) {
    for (int mt = 0; mt < 4; mt++) {
      int row0 = m0 + wm * 64 + mt * 16 + quad * 4;
      int b = row0 >> 11, s = row0 & 2047;
      for (int nt = 0; nt < 4; nt++) {
        int col = n0 + wn * 64 + nt * 16 + l16;
        float bv = bias[col];
        uint2 u;
        u.x = pack2(acc[mt][nt][0] + bv, acc[mt][nt][1] + bv);
        u.y = pack2(acc[mt][nt][2] + bv, acc[mt][nt][3] + bv);
        *(uint2*)&vt[(size_t)(b * 1024 + (col - 2048)) * S_ + s] = u;
      }
    }
  } else {
    for (int mt = 0; mt < 4; mt++) {
      int row = m0 + wm * 64 + mt * 16 + quad * 4;
      for (int nt = 0; nt < 4; nt++) {
        int col = n0 + wn * 64 + nt * 16 + l16;
        float bv = bias[col];
        for (int r = 0; r < 4; r++) {
          float v = acc[mt][nt][r] + bv;
          if (OUT_BF16) ((unsigned short*)Cout)[(size_t)(row + r) * N + col] = f2b(v);
          else          ((float*)Cout)[(size_t)(row + r) * N + col] = v;
        }
      }
    }
  }
}

// ---------- flash attention (causal), S^T layout, 40 KB LDS ----------
// Round-5 body (32 q/wave, per-g sequential 8 KB P buffer) at launch_bounds
// (256,3): round-5's (256,4) spilled (VGPR capped 64, WRITE 162 MB); at (256,3)
// regs ~84+32 -> 4 waves/SIMD, LDS 40 KB -> 4 blocks/CU = 16 waves/CU.
// 1D grid long-first: qt = 15-(bx>>6), bh = bx&63.
__global__ __launch_bounds__(256, 3) void k_attn(
    const unsigned short* __restrict__ qkv,  // [B*S][3H] bf16 (Q,K valid)
    const unsigned short* __restrict__ vt,   // [B*NH*HD][S] bf16
    unsigned short* __restrict__ outb) {     // [B*S][H] bf16
  __shared__ __align__(16) unsigned short Ks [2][64 * 64];  // [kv][hd] swizzled
  __shared__ __align__(16) unsigned short VTs[2][64 * 64];  // [hd][kv] swizzled
  __shared__ __align__(16) unsigned short Ps[4][16 * 64];   // per-wave [q][kv] swizzled

  const int tid  = threadIdx.x;
  const int lane = tid & 63, w = tid >> 6;
  const int quad = lane >> 4, l16 = lane & 15;
  const int qt = (S_ / 128 - 1) - (blockIdx.x >> 6);  // long blocks dispatch first
  const int bh = blockIdx.x & 63;
  const int b = bh >> 4, h = bh & 15;
  const int qwv = qt * 128 + w * 32;
  const int wv2 = w & 1;

  // Q B-fragments (S^T = K * Q^T): B[k=d][n=q], lane n=l16, k=quad*8+j
  short8 qf[2][2];
  for (int g = 0; g < 2; g++)
    for (int kh = 0; kh < 2; kh++)
      qf[g][kh] = *(const short8*)&qkv[(size_t)(b * S_ + qwv + g * 16 + l16) * (3 * H_)
                                       + h * HD_ + kh * 32 + quad * 8];

  floatx4 oacc[2][4];
  float lsum[2] = {0.f, 0.f};
  for (int g = 0; g < 2; g++)
    for (int ct = 0; ct < 4; ct++) oacc[g][ct] = (floatx4){0.f, 0.f, 0.f, 0.f};

  auto stage = [&](int kt, int bufi) {
    if (w < 2) {
      for (int j = 0; j < 4; j++) {
        int c = wv2 * 256 + j * 64 + lane;  // 0..511
        int row = c >> 3, c8 = (c & 7) ^ (row & 7);
        async16(&Ks[bufi][c * 8],
                &qkv[(size_t)(b * S_ + kt * 64 + row) * (3 * H_) + H_ + h * HD_ + c8 * 8]);
      }
    } else {
      for (int j = 0; j < 4; j++) {
        int c = wv2 * 256 + j * 64 + lane;
        int row = c >> 3, c8 = (c & 7) ^ (row & 7);
        async16(&VTs[bufi][c * 8],
                &vt[(size_t)(bh * HD_ + row) * S_ + kt * 64 + c8 * 8]);
      }
    }
  };

  unsigned short* Pw = &Ps[w][0];

  const int ktmax = 2 * qt + 1;
  stage(0, 0);
  for (int kt = 0; kt <= ktmax; kt++) {
    const int cur = kt & 1;
    __syncthreads();                          // buf[cur] visible; prev reads done
    if (kt < ktmax) stage(kt + 1, cur ^ 1);   // prefetch, hidden behind compute

    if (kt * 64 <= qwv + 31) {
      const bool need_mask = (kt * 64 + 63 > qwv);

      // V A-fragments: A[m=d][k=kv]
      short8 vf[4][2];
      for (int ct = 0; ct < 4; ct++)
        for (int kh = 0; kh < 2; kh++) {
          int vrow = ct * 16 + l16;
          vf[ct][kh] = *(const short8*)&VTs[cur][(vrow * 8 + ((kh * 4 + quad) ^ (vrow & 7))) * 8];
        }

      // S^T = K Q^T -> p (packed into regs)
      uint2 pk[2][4];
      for (int ct = 0; ct < 4; ct++) {
        int krow = ct * 16 + l16;
        short8 kf0 = *(const short8*)&Ks[cur][(krow * 8 + ((0 + quad) ^ (krow & 7))) * 8];
        short8 kf1 = *(const short8*)&Ks[cur][(krow * 8 + ((4 + quad) ^ (krow & 7))) * 8];
        for (int g = 0; g < 2; g++) {
          floatx4 z = (floatx4){0.f, 0.f, 0.f, 0.f};
          z = __builtin_amdgcn_mfma_f32_16x16x32_bf16(kf0, qf[g][0], z, 0, 0, 0);
          z = __builtin_amdgcn_mfma_f32_16x16x32_bf16(kf1, qf[g][1], z, 0, 0, 0);
          // lane: q = qwv+g*16+l16 fixed; kv = kt*64+ct*16+quad*4+r
          float p[4];
          if (need_mask) {
            int kvb = kt * 64 + ct * 16 + quad * 4;
            int q = qwv + g * 16 + l16;
            for (int r = 0; r < 4; r++)
              p[r] = (kvb + r <= q) ? __expf(z[r] * 0.125f) : 0.f;
          } else {
            for (int r = 0; r < 4; r++) p[r] = __expf(z[r] * 0.125f);
          }
          lsum[g] += (p[0] + p[1]) + (p[2] + p[3]);
          pk[g][ct].x = (unsigned int)f2b_fast(p[0]) | ((unsigned int)f2b_fast(p[1]) << 16);
          pk[g][ct].y = (unsigned int)f2b_fast(p[2]) | ((unsigned int)f2b_fast(p[3]) << 16);
        }
      }

      // per-g: P round-trip through 2 KB swizzled buffer, then PV MFMAs.
      // (DS ops in-order per wave -> WAR-safe reuse across g)
      for (int g = 0; g < 2; g++) {
        for (int ct = 0; ct < 4; ct++) {
          int slot = (ct * 2 + (quad >> 1)) ^ (l16 & 7);
          *(uint2*)&Pw[l16 * 64 + slot * 8 + (quad & 1) * 4] = pk[g][ct];
        }
        for (int kh = 0; kh < 2; kh++) {
          short8 pf = *(const short8*)&Pw[l16 * 64 + ((kh * 4 + quad) ^ (l16 & 7)) * 8];
          for (int ct = 0; ct < 4; ct++)
            oacc[g][ct] = __builtin_amdgcn_mfma_f32_16x16x32_bf16(vf[ct][kh], pf, oacc[g][ct], 0, 0, 0);
        }
      }
    }
  }

  // finish row sums: reduce across quads (lanes sharing l16 share q)
  for (int g = 0; g < 2; g++) {
    lsum[g] += __shfl_xor(lsum[g], 16);
    lsum[g] += __shfl_xor(lsum[g], 32);
  }

  // epilogue: lane holds q=l16 fixed, d=ct*16+quad*4+r -> packed 8B stores
  for (int g = 0; g < 2; g++) {
    float inv = 1.0f / lsum[g];
    int q = qwv + g * 16 + l16;
    for (int ct = 0; ct < 4; ct++) {
      uint2 u;
      u.x = pack2(oacc[g][ct][0] * inv, oacc[g][ct][1] * inv);
      u.y = pack2(oacc[g][ct][2] * inv, oacc[g][ct][3] * inv);
      *(uint2*)&outb[(size_t)(b * S_ + q) * H_ + h * HD_ + ct * 16 + quad * 4] = u;
    }
  }
}

extern "C" void kernel_launch(void* const* d_in, const int* in_sizes, int n_in,
                              void* d_out, int out_size, void* d_ws, size_t ws_size,
                              hipStream_t stream) {
  const float* x     = (const float*)d_in[0];
  const float* w_qkv = (const float*)d_in[1];
  const float* b_qkv = (const float*)d_in[2];
  const float* w_out = (const float*)d_in[3];
  const float* b_out = (const float*)d_in[4];

  char* ws = (char*)d_ws;
  size_t off = 0;
  auto alloc = [&](size_t bytes) -> void* {
    void* p = ws + off;
    off = (off + bytes + 255) & ~(size_t)255;
    return p;
  };
  unsigned short* xb    = (unsigned short*)alloc((size_t)B_ * S_ * H_ * 2);
  unsigned short* wqkvT = (unsigned short*)alloc((size_t)3 * H_ * H_ * 2);
  unsigned short* woutT = (unsigned short*)alloc((size_t)H_ * H_ * 2);
  unsigned short* qkv   = (unsigned short*)alloc((size_t)B_ * S_ * 3 * H_ * 2);
  unsigned short* ao    = (unsigned short*)alloc((size_t)B_ * S_ * H_ * 2);
  unsigned short* vtb   = (unsigned short*)alloc((size_t)B_ * NH_ * HD_ * S_ * 2);

  // merged prologue: cast x (8192 blocks) + transpose w_qkv (3072) + w_out (1024)
  k_prep<<<8192 + 3072 + 1024, 256, 0, stream>>>(x, w_qkv, w_out, xb, wqkvT, woutT);

  // QKV projection; V columns go transposed straight into vtb
  k_gemm_bt<true ><<<dim3(3 * H_ / 128, B_ * S_ / 128), 256, 0, stream>>>(
      xb, wqkvT, b_qkv, qkv, vtb, B_ * S_, 3 * H_, H_);

  k_attn<<<(S_ / 128) * 64, 256, 0, stream>>>(qkv, vtb, ao);

  k_gemm_bt<false><<<dim3(H_ / 128, B_ * S_ / 128), 256, 0, stream>>>(
      ao, woutT, b_out, (float*)d_out, nullptr, B_ * S_, H_, H_);
}